// Round 11
// baseline (2476.799 us; speedup 1.0000x reference)
//
#include <hip/hip_runtime.h>
#include <hip/hip_bf16.h>

#define NB 4
#define NPTS 8192
#define CIN 32
#define COUT 64
#define MOUT 2048   // NPTS / STRIDE
#define KNN 16
#define EPSBN 1e-5f

typedef float f32x2 __attribute__((ext_vector_type(2)));

// ---------------------------------------------------------------------------
// True packed-f32 ops via asm (opcodes proven to assemble on gfx950 in r5).
// IEEE per-half add/mul, RTNE == v_add_f32/v_mul_f32 -> bit-exact vs XLA.
// ---------------------------------------------------------------------------
__device__ inline f32x2 pk_add(f32x2 a, f32x2 b) {
    f32x2 r;
    asm("v_pk_add_f32 %0, %1, %2" : "=v"(r) : "v"(a), "v"(b));
    return r;
}
__device__ inline f32x2 pk_mul(f32x2 a, f32x2 b) {
    f32x2 r;
    asm("v_pk_mul_f32 %0, %1, %2" : "=v"(r) : "v"(a), "v"(b));
    return r;
}

// ---------------------------------------------------------------------------
// Setup: fold BN into conv weights.  w1s[o][c] = w1[o][c]*a1[o], c1[o]=b1-m1*a1
// wbuf layout (floats): [0,2240) w1s | [2240,2304) c1 | [2304,6400) w2s | [6400,6464) c2
// ---------------------------------------------------------------------------
__global__ void setup_kernel(const float* __restrict__ w1, const float* __restrict__ g1,
                             const float* __restrict__ b1, const float* __restrict__ m1,
                             const float* __restrict__ v1, const float* __restrict__ w2,
                             const float* __restrict__ g2, const float* __restrict__ b2,
                             const float* __restrict__ m2, const float* __restrict__ v2,
                             float* __restrict__ wbuf) {
    int o = threadIdx.x;
    if (o >= 64) return;
    float a1 = g1[o] * rsqrtf(v1[o] + EPSBN);
    wbuf[2240 + o] = b1[o] - m1[o] * a1;
    for (int c = 0; c < 35; ++c) wbuf[o * 35 + c] = w1[o * 35 + c] * a1;
    float a2 = g2[o] * rsqrtf(v2[o] + EPSBN);
    wbuf[6400 + o] = b2[o] - m2[o] * a2;
    for (int c = 0; c < 64; ++c) wbuf[2304 + o * 64 + c] = w2[o * 64 + c] * a2;
}

// ---------------------------------------------------------------------------
// Transpose x (B,C,N) -> xt (B,N,C) with LDS tiles (coalesced both sides)
// ---------------------------------------------------------------------------
__global__ __launch_bounds__(256) void transpose_kernel(const float* __restrict__ x,
                                                        float* __restrict__ xt) {
    __shared__ float tile[CIN][65];
    int b = blockIdx.y;
    int n0 = blockIdx.x * 64;
    int tid = threadIdx.x;
#pragma unroll
    for (int r = 0; r < 8; ++r) {
        int i = r * 256 + tid;
        int c = i >> 6, n = i & 63;
        tile[c][n] = x[((size_t)b * CIN + c) * NPTS + n0 + n];
    }
    __syncthreads();
#pragma unroll
    for (int r = 0; r < 8; ++r) {
        int i = r * 256 + tid;
        int n = i >> 5, c = i & 31;
        xt[((size_t)b * NPTS + n0 + n) * CIN + c] = tile[c][n];
    }
}

// ---------------------------------------------------------------------------
// FPS v8: v7 structure (512 thr, 16 pts/thread, DPP value-max + bit-scan
// index recovery, parity-buffered cross-wave u64 butterfly) with phase A in
// TRUE packed-f32 asm. Key vs r5's failed asm version: dmin stays a SCALAR
// array -- v_min_f32 reads d.x/d.y in place (sub-register read is free), no
// f32x2 repack writeback churn. Point regs stay f32x2 (the pk operands).
// Exactness: p+(-l) == p-l (IEEE), (dx2+dy2)+dz2 order kept, pk halves are
// plain f32 RTNE mul/add; argmax = first occurrence of max (descending slot
// scan -> ballot -> u64 (val<<32)|~idx across waves). Distances >= 0 so
// bit-equality == float equality.
// ---------------------------------------------------------------------------
#define FPS_PT 16
__global__ __launch_bounds__(512) void fps_kernel(const float* __restrict__ p1,
                                                  float* __restrict__ p2out) {
    int b = blockIdx.x;
    int tid = threadIdx.x;
    int lane = tid & 63;
    int wv = tid >> 6;                        // 0..7
    const float* P = p1 + (size_t)b * NPTS * 3;

    __shared__ float lp[NPTS * 3];            // 96 KiB point stage
    __shared__ unsigned long long warr[2][8];

    const float4* P4 = (const float4*)P;
    float4* L4 = (float4*)lp;
#pragma unroll
    for (int r = 0; r < 12; ++r) {
        int i = r * 512 + tid;
        L4[i] = P4[i];
    }
    __syncthreads();

    f32x2 px[8], py[8], pz[8];
    float dmin[FPS_PT];
    int base = tid * FPS_PT;
#pragma unroll
    for (int s = 0; s < 8; ++s) {
        int j = (base + 2 * s) * 3;
        px[s] = (f32x2){lp[j + 0], lp[j + 3]};
        py[s] = (f32x2){lp[j + 1], lp[j + 4]};
        pz[s] = (f32x2){lp[j + 2], lp[j + 5]};
        dmin[2 * s] = 1e10f;
        dmin[2 * s + 1] = 1e10f;
        // pin: opaque producer -> compiler cannot re-load from LDS in the loop
        asm volatile("" : "+v"(px[s]), "+v"(py[s]), "+v"(pz[s]));
    }

    float lx = lp[0], ly = lp[1], lz = lp[2];
    if (tid == 0) {
        p2out[(size_t)(b * MOUT) * 3 + 0] = lx;
        p2out[(size_t)(b * MOUT) * 3 + 1] = ly;
        p2out[(size_t)(b * MOUT) * 3 + 2] = lz;
    }

    for (int m = 1; m < MOUT; ++m) {
        // ---- phase A: packed distance, scalar dmin update ----
        float nlx = -lx, nly = -ly, nlz = -lz;
        f32x2 cx = {nlx, nlx}, cy = {nly, nly}, cz = {nlz, nlz};
#pragma unroll
        for (int s = 0; s < 8; ++s) {
            f32x2 dx = pk_add(px[s], cx);          // p + (-l) == p - l, exact
            f32x2 dy = pk_add(py[s], cy);
            f32x2 dz = pk_add(pz[s], cz);
            f32x2 xx = pk_mul(dx, dx);
            f32x2 yy = pk_mul(dy, dy);
            f32x2 zz = pk_mul(dz, dz);
            f32x2 d = pk_add(pk_add(xx, yy), zz);  // (dx2+dy2)+dz2
            dmin[2 * s] = fminf(dmin[2 * s], d.x);       // v_min_f32 on pair-lo
            dmin[2 * s + 1] = fminf(dmin[2 * s + 1], d.y); // v_min_f32 on pair-hi
        }
        // ---- scalar fmax tree (depth 4) over updated dmin ----
        float a0 = fmaxf(dmin[0], dmin[1]),   a1 = fmaxf(dmin[2], dmin[3]);
        float a2 = fmaxf(dmin[4], dmin[5]),   a3 = fmaxf(dmin[6], dmin[7]);
        float a4 = fmaxf(dmin[8], dmin[9]),   a5 = fmaxf(dmin[10], dmin[11]);
        float a6 = fmaxf(dmin[12], dmin[13]), a7 = fmaxf(dmin[14], dmin[15]);
        float b0 = fmaxf(a0, a1), b1 = fmaxf(a2, a3);
        float b2 = fmaxf(a4, a5), b3 = fmaxf(a6, a7);
        float bv = fmaxf(fmaxf(b0, b1), fmaxf(b2, b3));
        // ---- wave value-max: 4x DPP row_shr + xor16 swizzle + xor32 ----
        float x0 = bv;
        {
            int xi, sh;
            xi = __float_as_int(x0);
            sh = __builtin_amdgcn_update_dpp(xi, xi, 0x111, 0xF, 0xF, false);
            x0 = fmaxf(x0, __int_as_float(sh));
            xi = __float_as_int(x0);
            sh = __builtin_amdgcn_update_dpp(xi, xi, 0x112, 0xF, 0xF, false);
            x0 = fmaxf(x0, __int_as_float(sh));
            xi = __float_as_int(x0);
            sh = __builtin_amdgcn_update_dpp(xi, xi, 0x114, 0xF, 0xF, false);
            x0 = fmaxf(x0, __int_as_float(sh));
            xi = __float_as_int(x0);
            sh = __builtin_amdgcn_update_dpp(xi, xi, 0x118, 0xF, 0xF, false);
            x0 = fmaxf(x0, __int_as_float(sh));
            x0 = fmaxf(x0, __int_as_float(
                     __builtin_amdgcn_ds_swizzle(__float_as_int(x0), 0x401F)));
            x0 = fmaxf(x0, __shfl_xor(x0, 32));
        }
        unsigned g = (unsigned)__builtin_amdgcn_readlane(__float_as_int(x0), 15);
        // ---- index recovery: first (lane, slot) with bits(dmin)==g ----
        int loc = FPS_PT;
#pragma unroll
        for (int s = FPS_PT - 1; s >= 0; --s)
            if (__float_as_uint(dmin[s]) == g) loc = s;
        unsigned long long bal = __ballot(loc < FPS_PT);
        int l = __ffsll((long long)bal) - 1;
        int widx_w = __shfl(base + loc, l);
        // ---- cross-wave: per-wave slot write + 3-step u64 butterfly ----
        int par = m & 1;
        if (lane == 0) {
            unsigned long long pk =
                ((unsigned long long)g << 32) | (unsigned long long)(unsigned)(~widx_w);
            warr[par][wv] = pk;
        }
        __syncthreads();
        unsigned long long e = warr[par][lane & 7];
#pragma unroll
        for (int off = 1; off <= 4; off <<= 1) {
            unsigned long long o = __shfl_xor(e, off);
            if (o > e) e = o;
        }
        int widx = (int)(~(unsigned)(e & 0xffffffffull));
        int wj = widx * 3;
        lx = lp[wj + 0];
        ly = lp[wj + 1];
        lz = lp[wj + 2];
        if (tid == 0) {
            p2out[((size_t)b * MOUT + m) * 3 + 0] = lx;
            p2out[((size_t)b * MOUT + m) * 3 + 1] = ly;
            p2out[((size_t)b * MOUT + m) * 3 + 2] = lz;
        }
    }
}

// ---------------------------------------------------------------------------
// kNN: one wave per query. Distributed sorted top-16 in lanes 0..15,
// ballot-compacted insertion. d2 mirrors reference formula exactly.
// ---------------------------------------------------------------------------
__global__ __launch_bounds__(256) void knn_kernel(const float* __restrict__ p1,
                                                  const float* __restrict__ p2,
                                                  int* __restrict__ nnout) {
    int tid = threadIdx.x;
    int lane = tid & 63, wid = tid >> 6;
    int qid = blockIdx.x * 4 + wid;          // 0..8191
    int b = qid >> 11;
    const float* Pb = p1 + (size_t)b * NPTS * 3;
    const float* q = p2 + (size_t)qid * 3;
    float qx = q[0], qy = q[1], qz = q[2];
    float s2q = __fadd_rn(__fadd_rn(__fmul_rn(qx, qx), __fmul_rn(qy, qy)),
                          __fmul_rn(qz, qz));

    float tval = 3.0e38f;   // distributed sorted list (lanes 0..15)
    int   tidx = -1;
    float tau = 3.0e38f;

    for (int n0 = 0; n0 < NPTS; n0 += 64) {
        int n = n0 + lane;
        const float* pp = Pb + n * 3;
        float px = pp[0], py = pp[1], pz = pp[2];
        float s1n = __fadd_rn(__fadd_rn(__fmul_rn(px, px), __fmul_rn(py, py)),
                              __fmul_rn(pz, pz));
        float dot = __fadd_rn(__fadd_rn(__fmul_rn(qx, px), __fmul_rn(qy, py)),
                              __fmul_rn(qz, pz));
        float d2 = __fsub_rn(__fadd_rn(s2q, s1n), __fmul_rn(2.0f, dot));

        unsigned long long act = __ballot(d2 < tau);
        while (act) {
            int l = __ffsll(act) - 1;
            float dd = __shfl(d2, l);
            int   nn_ = __shfl(n, l);
            unsigned long long mle = __ballot(lane < 16 && tval <= dd);
            int pos = __popcll(mle);                 // stable insert position
            float sv = __shfl_up(tval, 1);
            int   si = __shfl_up(tidx, 1);
            if (lane < 16) {
                if (lane == pos)      { tval = dd; tidx = nn_; }
                else if (lane > pos)  { tval = sv; tidx = si; }
            }
            tau = __shfl(tval, 15);
            act &= (act - 1);
            act &= __ballot(d2 < tau);
        }
    }
    if (lane < 16) nnout[(size_t)qid * KNN + lane] = tidx;
}

// ---------------------------------------------------------------------------
// Fused gather + conv1(BN-folded)+ReLU + conv2(BN-folded)+ReLU + max over K.
// ---------------------------------------------------------------------------
template <int XT>
__global__ __launch_bounds__(256) void conv_kernel(const float* __restrict__ p1,
                                                   const float* __restrict__ p2,
                                                   const float* __restrict__ xsrc,
                                                   const int* __restrict__ nn,
                                                   const float* __restrict__ wbuf,
                                                   float* __restrict__ y) {
    const float* w1s = wbuf;
    const float* c1s = wbuf + 2240;
    const float* w2s = wbuf + 2304;
    const float* c2s = wbuf + 6400;
    int tid = threadIdx.x;
    int lane = tid & 63, wid = tid >> 6;
    int qq = lane >> 4, k = lane & 15;
    int qid = (blockIdx.x * 4 + wid) * 4 + qq;   // 0..8191
    int b = qid >> 11, m = qid & 2047;
    int nk = nn[(size_t)qid * KNN + k];

    const float* qp = p2 + (size_t)qid * 3;
    const float* np = p1 + ((size_t)b * NPTS + nk) * 3;
    float h[35];
    h[0] = np[0] - qp[0];
    h[1] = np[1] - qp[1];
    h[2] = np[2] - qp[2];
    if (XT) {
        const float4* xr = (const float4*)(xsrc + ((size_t)b * NPTS + nk) * CIN);
#pragma unroll
        for (int q8 = 0; q8 < 8; ++q8) {
            float4 f = xr[q8];
            h[3 + q8 * 4 + 0] = f.x;
            h[3 + q8 * 4 + 1] = f.y;
            h[3 + q8 * 4 + 2] = f.z;
            h[3 + q8 * 4 + 3] = f.w;
        }
    } else {
#pragma unroll
        for (int c = 0; c < CIN; ++c)
            h[3 + c] = xsrc[((size_t)b * CIN + c) * NPTS + nk];
    }

    float acc2[64];
#pragma unroll
    for (int o2 = 0; o2 < 64; ++o2) acc2[o2] = c2s[o2];

    for (int o = 0; o < 64; ++o) {
        float a = c1s[o];
#pragma unroll
        for (int c = 0; c < 35; ++c) a = fmaf(h[c], w1s[o * 35 + c], a);
        a = fmaxf(a, 0.0f);
#pragma unroll
        for (int o2 = 0; o2 < 64; ++o2) acc2[o2] = fmaf(a, w2s[o2 * 64 + o], acc2[o2]);
    }

#pragma unroll
    for (int o2 = 0; o2 < 64; ++o2) {
        float v = fmaxf(acc2[o2], 0.0f);
        v = fmaxf(v, __shfl_xor(v, 8));
        v = fmaxf(v, __shfl_xor(v, 4));
        v = fmaxf(v, __shfl_xor(v, 2));
        v = fmaxf(v, __shfl_xor(v, 1));
        if ((lane & 15) == (o2 & 15))
            y[((size_t)b * COUT + o2) * MOUT + m] = v;
    }
}

// ---------------------------------------------------------------------------
extern "C" void kernel_launch(void* const* d_in, const int* in_sizes, int n_in,
                              void* d_out, int out_size, void* d_ws, size_t ws_size,
                              hipStream_t stream) {
    const float* p1 = (const float*)d_in[0];
    const float* x  = (const float*)d_in[1];
    const float* w1 = (const float*)d_in[2];
    const float* g1 = (const float*)d_in[3];
    const float* b1 = (const float*)d_in[4];
    const float* m1 = (const float*)d_in[5];
    const float* v1 = (const float*)d_in[6];
    const float* w2 = (const float*)d_in[7];
    const float* g2 = (const float*)d_in[8];
    const float* b2 = (const float*)d_in[9];
    const float* m2 = (const float*)d_in[10];
    const float* v2 = (const float*)d_in[11];

    float* p2o = (float*)d_out;                       // (B,M,3)
    float* yo  = p2o + (size_t)NB * MOUT * 3;         // (B,COUT,M)

    char* ws = (char*)d_ws;
    int*   nn   = (int*)ws;                            // 512 KiB
    float* wbuf = (float*)(ws + 512 * 1024);           // 25.9 KiB
    float* xt   = (float*)(ws + 1024 * 1024);          // 4 MiB
    bool use_xt = ws_size >= (size_t)(1024 * 1024) + (size_t)NB * NPTS * CIN * 4;

    setup_kernel<<<1, 64, 0, stream>>>(w1, g1, b1, m1, v1, w2, g2, b2, m2, v2, wbuf);
    if (use_xt)
        transpose_kernel<<<dim3(NPTS / 64, NB), 256, 0, stream>>>(x, xt);
    fps_kernel<<<NB, 512, 0, stream>>>(p1, p2o);
    knn_kernel<<<(NB * MOUT) / 4, 256, 0, stream>>>(p1, p2o, nn);
    if (use_xt)
        conv_kernel<1><<<(NB * MOUT) / 16, 256, 0, stream>>>(p1, p2o, xt, nn, wbuf, yo);
    else
        conv_kernel<0><<<(NB * MOUT) / 16, 256, 0, stream>>>(p1, p2o, x, nn, wbuf, yo);
}